// Round 13
// baseline (260.862 us; speedup 1.0000x reference)
//
#include <hip/hip_runtime.h>
#include <stdint.h>

typedef unsigned int uint32;
typedef _Float16 f16x8 __attribute__((ext_vector_type(8)));
typedef float f32x4 __attribute__((ext_vector_type(4)));
typedef float f4v __attribute__((ext_vector_type(4)));
typedef unsigned int u2v __attribute__((ext_vector_type(2)));

// ---------------------------------------------------------------------------
// GCN 2-layer. CSR via atomic-free 2-level bucket sort (XCD-aware chunking).
// dis folded into feature tables at mgemm epilogue (table[r]=dis[r]*(X@W)[r]).
// agg[c] = dv*( sum_e ew_e*table[r_e] + table[c] ) + b.
// NT (nontemporal) loads/stores on all once-touched streams so the 25.6MB
// gather table keeps the L2: prop outputs, record streams, mgemm X reads.
// GEMMs via mfma_f32_16x16x32_f16 (f32 accum).
// ---------------------------------------------------------------------------

#define NPBSH 6
#define NPB 64
#define PBLK 256
#define CAP 2048

__device__ inline int detect64(const int* __restrict__ e) {
    int z = 0;
#pragma unroll
    for (int i = 0; i < 16; ++i) z |= e[2 * i + 1];
    return z == 0;
}

__device__ inline int chunk_map(int blk) {  // XCD-contiguous chunk assignment
    return (blk & 7) * (PBLK / 8) + (blk >> 3);
}

// p1: per-chunk bucket histogram (LDS), no global atomics.
__global__ __launch_bounds__(512) void p1_hist(const void* __restrict__ ei, int E, int NB,
                                               int chunk, int* __restrict__ cnt_bb) {
    extern __shared__ int h[];
    const int t = threadIdx.x;
    const int blk = chunk_map(blockIdx.x);
    for (int i = t; i < NB; i += 512) h[i] = 0;
    __syncthreads();
    const int is64 = detect64((const int*)ei);
    const int* e32 = (const int*)ei;
    const long long* e64 = (const long long*)ei;
    const int e0 = blk * chunk;
    const int e1 = min(e0 + chunk, E);
    for (int e = e0 + t; e < e1; e += 512) {
        int c = is64 ? (int)__builtin_nontemporal_load(&e64[(size_t)E + e])
                     : __builtin_nontemporal_load(&e32[(size_t)E + e]);
        atomicAdd(&h[c >> NPBSH], 1);
    }
    __syncthreads();
    for (int i = t; i < NB; i += 512) cnt_bb[(size_t)blk * NB + i] = h[i];
}

// s1: per-bucket column scan over PBLK chunk-counts -> boff_rel + totals.
__global__ __launch_bounds__(PBLK) void s1_colscan(const int* __restrict__ cnt_bb,
                                                   int* __restrict__ boff_rel,
                                                   int* __restrict__ tb, int NB) {
    __shared__ int sm[PBLK];
    const int t = threadIdx.x, b = blockIdx.x;
    int v = cnt_bb[(size_t)t * NB + b];
    sm[t] = v;
    __syncthreads();
    for (int off = 1; off < PBLK; off <<= 1) {
        int u = (t >= off) ? sm[t - off] : 0;
        __syncthreads();
        sm[t] += u;
        __syncthreads();
    }
    boff_rel[(size_t)t * NB + b] = sm[t] - v;
    if (t == PBLK - 1) tb[b] = sm[PBLK - 1];
}

// s2: single-block chunked exclusive scan.
__global__ __launch_bounds__(1024) void scan_kernel(const int* __restrict__ cnt,
                                                    int* __restrict__ ptr, int n) {
    __shared__ int sm[1024];
    const int t = threadIdx.x;
    const int chunk = (n + 1023) / 1024;
    const int start = t * chunk;
    const int end = min(start + chunk, n);
    int s = 0;
    for (int i = start; i < end; ++i) s += cnt[i];
    sm[t] = s;
    __syncthreads();
    for (int off = 1; off < 1024; off <<= 1) {
        int v = (t >= off) ? sm[t - off] : 0;
        __syncthreads();
        sm[t] += v;
        __syncthreads();
    }
    int run = (t == 0) ? 0 : sm[t - 1];
    for (int i = start; i < end; ++i) { ptr[i] = run; run += cnt[i]; }
    if (start < n && end == n) ptr[n] = run;
}

// p2: bucketed append; packed 8B records {row | cl<<20, ew_bits}, NT stores.
__global__ __launch_bounds__(512) void p2_scatter(const void* __restrict__ ei,
                                                  const float* __restrict__ ew,
                                                  int E, int NB, int chunk,
                                                  const int* __restrict__ bstart,
                                                  const int* __restrict__ boff_rel,
                                                  long long* __restrict__ bktrec) {
    extern __shared__ int cur[];
    const int t = threadIdx.x;
    const int blk = chunk_map(blockIdx.x);
    for (int i = t; i < NB; i += 512)
        cur[i] = bstart[i] + boff_rel[(size_t)blk * NB + i];
    __syncthreads();
    const int is64 = detect64((const int*)ei);
    const int* e32 = (const int*)ei;
    const long long* e64 = (const long long*)ei;
    const int e0 = blk * chunk;
    const int e1 = min(e0 + chunk, E);
    for (int e = e0 + t; e < e1; e += 512) {
        int r, c;
        if (is64) {
            r = (int)__builtin_nontemporal_load(&e64[e]);
            c = (int)__builtin_nontemporal_load(&e64[(size_t)E + e]);
        } else {
            r = __builtin_nontemporal_load(&e32[e]);
            c = __builtin_nontemporal_load(&e32[(size_t)E + e]);
        }
        float w = __builtin_nontemporal_load(&ew[e]);
        int b = c >> NPBSH;
        int pos = atomicAdd(&cur[b], 1);
        long long rec = (long long)(unsigned int)(r | ((c & (NPB - 1)) << 20)) |
                        ((long long)__float_as_int(w) << 32);
        __builtin_nontemporal_store(rec, &bktrec[pos]);
    }
}

// p3: per-bucket CSR build in LDS + ptr + fused deg/dis.
__global__ __launch_bounds__(256) void p3_build(const int* __restrict__ bstart,
                                                const long long* __restrict__ bktrec,
                                                int* __restrict__ ptr, int* __restrict__ rows_s,
                                                float* __restrict__ ws_s, float* __restrict__ dis,
                                                int n, int NB, int E) {
    __shared__ int inp[CAP];
    __shared__ float inw[CAP];
    __shared__ int outr[CAP];
    __shared__ float outw[CAP];
    __shared__ int h[NPB], ex[NPB + 1], cu[NPB];
    const int t = threadIdx.x, b = blockIdx.x;
    const int base = bstart[b];
    const int eb = bstart[b + 1] - base;
    const int j0 = b << NPBSH;
    const int ncount = min(NPB, n - j0);
    if (t < NPB) { h[t] = 0; cu[t] = 0; }
    __syncthreads();

    if (eb <= CAP) {
        for (int i = t; i < eb; i += 256) {
            long long rc = __builtin_nontemporal_load(&bktrec[base + i]);
            int lo = (int)rc;
            inp[i] = lo;
            inw[i] = __int_as_float((int)(rc >> 32));
            atomicAdd(&h[(lo >> 20) & 63], 1);
        }
        __syncthreads();
        if (t == 0) {
            int run = 0;
            for (int j = 0; j < NPB; ++j) { ex[j] = run; run += h[j]; }
            ex[NPB] = run;
        }
        __syncthreads();
        for (int i = t; i < eb; i += 256) {
            int v = inp[i];
            int cl = (v >> 20) & 63;
            int d = ex[cl] + atomicAdd(&cu[cl], 1);
            outr[d] = v & 0xFFFFF;
            outw[d] = inw[i];
        }
        __syncthreads();
        for (int i = t; i < eb; i += 256) {
            __builtin_nontemporal_store(outr[i], &rows_s[base + i]);
            __builtin_nontemporal_store(outw[i], &ws_s[base + i]);
        }
        if (t < ncount) {
            ptr[j0 + t] = base + ex[t];
            float s = 0.f;
            for (int i = ex[t]; i < ex[t] + h[t]; ++i) s += outw[i];
            dis[j0 + t] = rsqrtf(s + 1.0f);
        }
    } else {  // fallback (eb > CAP): global two-pass, still correct
        for (int i = t; i < eb; i += 256) {
            long long rc = __builtin_nontemporal_load(&bktrec[base + i]);
            atomicAdd(&h[((int)rc >> 20) & 63], 1);
        }
        __syncthreads();
        if (t == 0) {
            int run = 0;
            for (int j = 0; j < NPB; ++j) { ex[j] = run; run += h[j]; }
            ex[NPB] = run;
        }
        __syncthreads();
        for (int i = t; i < eb; i += 256) {
            long long rc = __builtin_nontemporal_load(&bktrec[base + i]);
            int lo = (int)rc;
            int cl = (lo >> 20) & 63;
            int d = ex[cl] + atomicAdd(&cu[cl], 1);
            rows_s[base + d] = lo & 0xFFFFF;
            ws_s[base + d] = __int_as_float((int)(rc >> 32));
        }
        __syncthreads();
        if (t < ncount) {
            ptr[j0 + t] = base + ex[t];
            float s = 0.f;
            for (int i = base + ex[t]; i < base + ex[t] + h[t]; ++i) s += ws_s[i];
            dis[j0 + t] = rsqrtf(s + 1.0f);
        }
    }
    if (b == NB - 1 && t == 0) ptr[n] = E;
    if (b == NB - 1 && t < 8) {  // zero pad: masked over-reads see row 0 / w 0
        rows_s[E + t] = 0;
        ws_s[E + t] = 0.f;
    }
}

__device__ inline uint32 pack2h(float a, float b) {
    unsigned short ua = __builtin_bit_cast(unsigned short, (_Float16)a);
    unsigned short ub = __builtin_bit_cast(unsigned short, (_Float16)b);
    return (uint32)ua | ((uint32)ub << 16);
}
__device__ inline float h2lo(uint32 g) {
    return (float)__builtin_bit_cast(_Float16, (unsigned short)(g & 0xFFFFu));
}
__device__ inline float h2hi(uint32 g) {
    return (float)__builtin_bit_cast(_Float16, (unsigned short)(g >> 16));
}

// Byte offset of fp16 element k within a 256B fragment-ordered row (same
// permutation applied to A and B keeps D = A*B invariant).
__device__ inline int kposb(int k) {
    return ((k >> 5) << 6) + (((k >> 2) & 3) << 4) + (((k >> 4) & 1) << 3) + ((k & 3) << 1);
}

// ---------------------------------------------------------------------------
// Y[n,DOUT] = dis[row] * (X[n,128] @ W[128,DOUT]) via mfma_f32_16x16x32_f16.
// X staged with NT loads (once-touched stream; preserves L2 for the tables).
// ---------------------------------------------------------------------------
template <int DOUT, bool PACKED>
__global__ __launch_bounds__(256, 2) void mgemm_kernel(const void* __restrict__ Xv,
                                                       const float* __restrict__ W,
                                                       const float* __restrict__ dis,
                                                       unsigned short* __restrict__ Y,
                                                       int n) {
    constexpr int NC = DOUT / 16;
    __shared__ __align__(16) unsigned short Xl[128 * 128];
    __shared__ __align__(16) unsigned short Wl[DOUT * 128];
    const int t = threadIdx.x;
    const int row0 = blockIdx.x * 128;

    for (int i = t * 4; i < 128 * 128; i += 1024) {
        int r = i >> 7, k = i & 127;
        uint2 st;
        if (PACKED) {
            u2v v = {0u, 0u};
            if (row0 + r < n)
                v = __builtin_nontemporal_load(
                    (const u2v*)((const uint32*)Xv + (size_t)(row0 + r) * 64 + (k >> 1)));
            st.x = v.x;
            st.y = v.y;
        } else {
            f4v v = {0.f, 0.f, 0.f, 0.f};
            if (row0 + r < n)
                v = __builtin_nontemporal_load(
                    (const f4v*)((const float*)Xv + (size_t)(row0 + r) * 128 + k));
            st.x = pack2h(v.x, v.y);
            st.y = pack2h(v.z, v.w);
        }
        *(uint2*)((char*)Xl + r * 256 + (kposb(k) ^ ((r & 7) << 4))) = st;
    }
    for (int i = t; i < 128 * (DOUT / 4); i += 256) {
        int k = i / (DOUT / 4);
        int c0 = (i % (DOUT / 4)) * 4;
        float4 wv = *(const float4*)(W + (size_t)k * DOUT + c0);
        float a[4] = {wv.x, wv.y, wv.z, wv.w};
        int kb = kposb(k);
#pragma unroll
        for (int j = 0; j < 4; ++j) {
            int c = c0 + j;
            *(unsigned short*)((char*)Wl + c * 256 + (kb ^ ((c & 7) << 4))) =
                __builtin_bit_cast(unsigned short, (_Float16)a[j]);
        }
    }
    __syncthreads();

    const int l = t & 63;
    const int w = t >> 6;
    const int lr = l & 15;
    const int lq = l >> 4;
    const int rbase = w * 32;
    const int swz = (lr & 7) << 4;

    f32x4 acc[2][NC];
#pragma unroll
    for (int i = 0; i < 2; ++i)
#pragma unroll
        for (int c = 0; c < NC; ++c) acc[i][c] = (f32x4){0.f, 0.f, 0.f, 0.f};

#pragma unroll
    for (int ks = 0; ks < 4; ++ks) {
        const int fo = ks * 64 + lq * 16;
        f16x8 a0 = *(const f16x8*)((const char*)Xl + (rbase + lr) * 256 + (fo ^ swz));
        f16x8 a1 = *(const f16x8*)((const char*)Xl + (rbase + 16 + lr) * 256 + (fo ^ swz));
#pragma unroll
        for (int c = 0; c < NC; ++c) {
            f16x8 b = *(const f16x8*)((const char*)Wl + (c * 16 + lr) * 256 + (fo ^ swz));
            acc[0][c] = __builtin_amdgcn_mfma_f32_16x16x32_f16(a0, b, acc[0][c], 0, 0, 0);
            acc[1][c] = __builtin_amdgcn_mfma_f32_16x16x32_f16(a1, b, acc[1][c], 0, 0, 0);
        }
    }

#pragma unroll
    for (int i = 0; i < 2; ++i) {
#pragma unroll
        for (int reg = 0; reg < 4; ++reg) {
            int row = row0 + rbase + i * 16 + lq * 4 + reg;
            if (row < n) {
                float dvv = dis[row];
#pragma unroll
                for (int c = 0; c < NC; ++c)
                    Y[(size_t)row * DOUT + c * 16 + lr] =
                        __builtin_bit_cast(unsigned short, (_Float16)(dvv * acc[i][c][reg]));
            }
        }
    }
}

// One wave per node, D=128: lane covers dims 2*lane..2*lane+1 (one fp16x2).
// table pre-scaled by dis[row]; edge meta via wave-uniform scalar loads.
// Output NT store (streaming; keep L2 for the gather table).
__global__ __launch_bounds__(256) void prop128_kernel(const uint32* __restrict__ xwb,
                                                      const float* __restrict__ dis,
                                                      const int* __restrict__ ptr,
                                                      const int* __restrict__ rows_s,
                                                      const float* __restrict__ ws_s,
                                                      const float* __restrict__ bias,
                                                      uint32* __restrict__ out, int n) {
    const int wid = threadIdx.x >> 6;
    const int lane = threadIdx.x & 63;
    const int v = blockIdx.x * 4 + wid;
    if (v >= n) return;

    const int beg = __builtin_amdgcn_readfirstlane(ptr[v]);
    const int end = __builtin_amdgcn_readfirstlane(ptr[v + 1]);
    const float dv = dis[v];

    float acc0 = 0.f, acc1 = 0.f;
    int e = beg;
    int head = (beg + 3) & ~3;
    if (head > end) head = end;
    for (; e < head; ++e) {
        int r = rows_s[e];
        float w = ws_s[e];
        uint32 g = xwb[(size_t)r * 64 + lane];
        acc0 += w * h2lo(g);
        acc1 += w * h2hi(g);
    }
#pragma unroll 4
    for (; e + 4 <= end; e += 4) {
        int4 r4 = *(const int4*)(rows_s + e);
        float4 w4 = *(const float4*)(ws_s + e);
        uint32 g0 = xwb[(size_t)r4.x * 64 + lane];
        uint32 g1 = xwb[(size_t)r4.y * 64 + lane];
        uint32 g2 = xwb[(size_t)r4.z * 64 + lane];
        uint32 g3 = xwb[(size_t)r4.w * 64 + lane];
        acc0 += w4.x * h2lo(g0); acc1 += w4.x * h2hi(g0);
        acc0 += w4.y * h2lo(g1); acc1 += w4.y * h2hi(g1);
        acc0 += w4.z * h2lo(g2); acc1 += w4.z * h2hi(g2);
        acc0 += w4.w * h2lo(g3); acc1 += w4.w * h2hi(g3);
    }
    for (; e < end; ++e) {
        int r = rows_s[e];
        float w = ws_s[e];
        uint32 g = xwb[(size_t)r * 64 + lane];
        acc0 += w * h2lo(g);
        acc1 += w * h2hi(g);
    }

    uint32 g = xwb[(size_t)v * 64 + lane];  // self: dv*table[v] = dis^2*xw[v]
    float r0 = dv * (acc0 + h2lo(g)) + bias[lane * 2];
    float r1 = dv * (acc1 + h2hi(g)) + bias[lane * 2 + 1];
    r0 = fmaxf(r0, 0.f);
    r1 = fmaxf(r1, 0.f);
    __builtin_nontemporal_store(pack2h(r0, r1), &out[(size_t)v * 64 + lane]);
}

// One wave per node, D=64: lane halves process 2 edges/iter; dims via
// dlane=lane&31 (fp16x2 each). shfl_xor(32) combine; f32 NT output.
__global__ __launch_bounds__(256) void prop64_kernel(const uint32* __restrict__ xwb,
                                                     const float* __restrict__ dis,
                                                     const int* __restrict__ ptr,
                                                     const int* __restrict__ rows_s,
                                                     const float* __restrict__ ws_s,
                                                     const float* __restrict__ bias,
                                                     float* __restrict__ out, int n) {
    const int wid = threadIdx.x >> 6;
    const int lane = threadIdx.x & 63;
    const int half = lane >> 5;
    const int dlane = lane & 31;
    const int v = blockIdx.x * 4 + wid;
    if (v >= n) return;

    const int beg = __builtin_amdgcn_readfirstlane(ptr[v]);
    const int end = __builtin_amdgcn_readfirstlane(ptr[v + 1]);
    const float dv = dis[v];

    float acc0 = 0.f, acc1 = 0.f;
    int e = beg;
    int head = (beg + 3) & ~3;
    if (head > end) head = end;
    for (; e < head; ++e) {
        int r = rows_s[e];
        float w = half ? 0.f : ws_s[e];
        uint32 g = xwb[(size_t)r * 32 + dlane];
        acc0 += w * h2lo(g);
        acc1 += w * h2hi(g);
    }
#pragma unroll 4
    for (; e + 4 <= end; e += 4) {
        int4 r4 = *(const int4*)(rows_s + e);
        float4 w4 = *(const float4*)(ws_s + e);
        int rA = half ? r4.y : r4.x;
        float wA = half ? w4.y : w4.x;
        int rB = half ? r4.w : r4.z;
        float wB = half ? w4.w : w4.z;
        uint32 gA = xwb[(size_t)rA * 32 + dlane];
        uint32 gB = xwb[(size_t)rB * 32 + dlane];
        acc0 += wA * h2lo(gA); acc1 += wA * h2hi(gA);
        acc0 += wB * h2lo(gB); acc1 += wB * h2hi(gB);
    }
    if (e + 2 <= end) {
        int2 r2 = *(const int2*)(rows_s + e);
        float2 w2 = *(const float2*)(ws_s + e);
        int r = half ? r2.y : r2.x;
        float w = half ? w2.y : w2.x;
        uint32 g = xwb[(size_t)r * 32 + dlane];
        acc0 += w * h2lo(g);
        acc1 += w * h2hi(g);
        e += 2;
    }
    if (e < end) {
        int r = rows_s[e];
        float w = half ? 0.f : ws_s[e];
        uint32 g = xwb[(size_t)r * 32 + dlane];
        acc0 += w * h2lo(g);
        acc1 += w * h2hi(g);
    }
    acc0 += __shfl_xor(acc0, 32);
    acc1 += __shfl_xor(acc1, 32);

    if (lane < 32) {
        uint32 g = xwb[(size_t)v * 32 + lane];
        float r0 = dv * (acc0 + h2lo(g)) + bias[lane * 2];
        float r1 = dv * (acc1 + h2hi(g)) + bias[lane * 2 + 1];
        unsigned long long o =
            (unsigned long long)(uint32)__float_as_int(r0) |
            ((unsigned long long)(uint32)__float_as_int(r1) << 32);
        __builtin_nontemporal_store(o, (unsigned long long*)(out + (size_t)v * 64 + lane * 2));
    }
}

extern "C" void kernel_launch(void* const* d_in, const int* in_sizes, int n_in,
                              void* d_out, int out_size, void* d_ws, size_t ws_size,
                              hipStream_t stream) {
    const float* x  = (const float*)d_in[0];
    const void*  ei = d_in[1];
    const float* ew = (const float*)d_in[2];
    const float* W1 = (const float*)d_in[3];
    const float* b1 = (const float*)d_in[4];
    const float* W2 = (const float*)d_in[5];
    const float* b2 = (const float*)d_in[6];
    float* out = (float*)d_out;

    const int n = in_sizes[0] / 128;
    const int E = in_sizes[2];
    const int NB = (n + NPB - 1) >> NPBSH;
    const int chunk = (E + PBLK - 1) / PBLK;

    char* p = (char*)d_ws;
    size_t o = 0;
    auto alloc = [&](size_t bytes) -> void* {
        void* q = p + o;
        o += (bytes + 255) & ~(size_t)255;
        return q;
    };
    int*       cnt_bb   = (int*)alloc((size_t)PBLK * NB * 4);
    int*       boff_rel = (int*)alloc((size_t)PBLK * NB * 4);
    int*       tb       = (int*)alloc((size_t)NB * 4);
    int*       bstart   = (int*)alloc(((size_t)NB + 1) * 4);
    int*       ptr      = (int*)alloc(((size_t)n + 1) * 4);
    float*     dis      = (float*)alloc((size_t)n * 4);
    long long* bktrec   = (long long*)alloc((size_t)E * 8);
    int*       rows_s   = (int*)alloc(((size_t)E + 8) * 4);
    float*     ws_s     = (float*)alloc(((size_t)E + 8) * 4);
    uint32*    bufA     = (uint32*)alloc((size_t)n * 64 * 4);  // dis-scaled xw tables
    uint32*    bufB     = (uint32*)alloc((size_t)n * 64 * 4);  // h fp16x2

    const int gblk = (n + 127) / 128;

    p1_hist<<<PBLK, 512, NB * 4, stream>>>(ei, E, NB, chunk, cnt_bb);
    s1_colscan<<<NB, PBLK, 0, stream>>>(cnt_bb, boff_rel, tb, NB);
    scan_kernel<<<1, 1024, 0, stream>>>(tb, bstart, NB);
    p2_scatter<<<PBLK, 512, NB * 4, stream>>>(ei, ew, E, NB, chunk, bstart, boff_rel, bktrec);
    p3_build<<<NB, 256, 0, stream>>>(bstart, bktrec, ptr, rows_s, ws_s, dis, n, NB, E);

    mgemm_kernel<128, false><<<gblk, 256, 0, stream>>>(x, W1, dis, (unsigned short*)bufA, n);
    prop128_kernel<<<(n + 3) / 4, 256, 0, stream>>>(bufA, dis, ptr, rows_s, ws_s, b1, bufB, n);
    mgemm_kernel<64, true><<<gblk, 256, 0, stream>>>(bufB, W2, dis, (unsigned short*)bufA, n);
    prop64_kernel<<<(n + 3) / 4, 256, 0, stream>>>(bufA, dis, ptr, rows_s, ws_s, b2, out, n);
}

// Round 14
// 222.766 us; speedup vs baseline: 1.1710x; 1.1710x over previous
//
#include <hip/hip_runtime.h>
#include <stdint.h>

typedef unsigned int uint32;
typedef _Float16 f16x8 __attribute__((ext_vector_type(8)));
typedef float f32x4 __attribute__((ext_vector_type(4)));

// ---------------------------------------------------------------------------
// GCN 2-layer. CSR via atomic-free 2-level bucket sort (XCD-aware chunking).
// dis folded into feature tables at mgemm epilogue (table[r]=dis[r]*(X@W)[r]).
// agg[c] = dv*( sum_e ew_e*table[r_e] + table[c] ) + b.
// GEMMs via mfma_f32_16x16x32_f16 (f32 accum); tables packed fp16x2.
// (R12's NT-hint experiment reverted: it cost L2 reuse in p3/mgemm2 and did
// not reduce the gather-table miss traffic.)
// ---------------------------------------------------------------------------

#define NPBSH 6
#define NPB 64
#define PBLK 256
#define CAP 2048

__device__ inline int detect64(const int* __restrict__ e) {
    int z = 0;
#pragma unroll
    for (int i = 0; i < 16; ++i) z |= e[2 * i + 1];
    return z == 0;
}

__device__ inline int chunk_map(int blk) {  // XCD-contiguous chunk assignment
    return (blk & 7) * (PBLK / 8) + (blk >> 3);
}

// p1: per-chunk bucket histogram (LDS), no global atomics.
__global__ __launch_bounds__(512) void p1_hist(const void* __restrict__ ei, int E, int NB,
                                               int chunk, int* __restrict__ cnt_bb) {
    extern __shared__ int h[];
    const int t = threadIdx.x;
    const int blk = chunk_map(blockIdx.x);
    for (int i = t; i < NB; i += 512) h[i] = 0;
    __syncthreads();
    const int is64 = detect64((const int*)ei);
    const int* e32 = (const int*)ei;
    const long long* e64 = (const long long*)ei;
    const int e0 = blk * chunk;
    const int e1 = min(e0 + chunk, E);
    for (int e = e0 + t; e < e1; e += 512) {
        int c = is64 ? (int)e64[(size_t)E + e] : e32[(size_t)E + e];
        atomicAdd(&h[c >> NPBSH], 1);
    }
    __syncthreads();
    for (int i = t; i < NB; i += 512) cnt_bb[(size_t)blk * NB + i] = h[i];
}

// s1: per-bucket column scan over PBLK chunk-counts -> boff_rel + totals.
__global__ __launch_bounds__(PBLK) void s1_colscan(const int* __restrict__ cnt_bb,
                                                   int* __restrict__ boff_rel,
                                                   int* __restrict__ tb, int NB) {
    __shared__ int sm[PBLK];
    const int t = threadIdx.x, b = blockIdx.x;
    int v = cnt_bb[(size_t)t * NB + b];
    sm[t] = v;
    __syncthreads();
    for (int off = 1; off < PBLK; off <<= 1) {
        int u = (t >= off) ? sm[t - off] : 0;
        __syncthreads();
        sm[t] += u;
        __syncthreads();
    }
    boff_rel[(size_t)t * NB + b] = sm[t] - v;
    if (t == PBLK - 1) tb[b] = sm[PBLK - 1];
}

// s2: single-block chunked exclusive scan.
__global__ __launch_bounds__(1024) void scan_kernel(const int* __restrict__ cnt,
                                                    int* __restrict__ ptr, int n) {
    __shared__ int sm[1024];
    const int t = threadIdx.x;
    const int chunk = (n + 1023) / 1024;
    const int start = t * chunk;
    const int end = min(start + chunk, n);
    int s = 0;
    for (int i = start; i < end; ++i) s += cnt[i];
    sm[t] = s;
    __syncthreads();
    for (int off = 1; off < 1024; off <<= 1) {
        int v = (t >= off) ? sm[t - off] : 0;
        __syncthreads();
        sm[t] += v;
        __syncthreads();
    }
    int run = (t == 0) ? 0 : sm[t - 1];
    for (int i = start; i < end; ++i) { ptr[i] = run; run += cnt[i]; }
    if (start < n && end == n) ptr[n] = run;
}

// p2: bucketed append; packed 8B records {row | cl<<20, ew_bits}.
__global__ __launch_bounds__(512) void p2_scatter(const void* __restrict__ ei,
                                                  const float* __restrict__ ew,
                                                  int E, int NB, int chunk,
                                                  const int* __restrict__ bstart,
                                                  const int* __restrict__ boff_rel,
                                                  int2* __restrict__ bktrec) {
    extern __shared__ int cur[];
    const int t = threadIdx.x;
    const int blk = chunk_map(blockIdx.x);
    for (int i = t; i < NB; i += 512)
        cur[i] = bstart[i] + boff_rel[(size_t)blk * NB + i];
    __syncthreads();
    const int is64 = detect64((const int*)ei);
    const int* e32 = (const int*)ei;
    const long long* e64 = (const long long*)ei;
    const int e0 = blk * chunk;
    const int e1 = min(e0 + chunk, E);
    for (int e = e0 + t; e < e1; e += 512) {
        int r, c;
        if (is64) { r = (int)e64[e]; c = (int)e64[(size_t)E + e]; }
        else      { r = e32[e];      c = e32[(size_t)E + e]; }
        int b = c >> NPBSH;
        int pos = atomicAdd(&cur[b], 1);
        bktrec[pos] = make_int2(r | ((c & (NPB - 1)) << 20), __float_as_int(ew[e]));
    }
}

// p3: per-bucket CSR build in LDS + ptr + fused deg/dis.
__global__ __launch_bounds__(256) void p3_build(const int* __restrict__ bstart,
                                                const int2* __restrict__ bktrec,
                                                int* __restrict__ ptr, int* __restrict__ rows_s,
                                                float* __restrict__ ws_s, float* __restrict__ dis,
                                                int n, int NB, int E) {
    __shared__ int inp[CAP];
    __shared__ float inw[CAP];
    __shared__ int outr[CAP];
    __shared__ float outw[CAP];
    __shared__ int h[NPB], ex[NPB + 1], cu[NPB];
    const int t = threadIdx.x, b = blockIdx.x;
    const int base = bstart[b];
    const int eb = bstart[b + 1] - base;
    const int j0 = b << NPBSH;
    const int ncount = min(NPB, n - j0);
    if (t < NPB) { h[t] = 0; cu[t] = 0; }
    __syncthreads();

    if (eb <= CAP) {
        for (int i = t; i < eb; i += 256) {
            int2 rc = bktrec[base + i];
            inp[i] = rc.x;
            inw[i] = __int_as_float(rc.y);
            atomicAdd(&h[(rc.x >> 20) & 63], 1);
        }
        __syncthreads();
        if (t == 0) {
            int run = 0;
            for (int j = 0; j < NPB; ++j) { ex[j] = run; run += h[j]; }
            ex[NPB] = run;
        }
        __syncthreads();
        for (int i = t; i < eb; i += 256) {
            int v = inp[i];
            int cl = (v >> 20) & 63;
            int d = ex[cl] + atomicAdd(&cu[cl], 1);
            outr[d] = v & 0xFFFFF;
            outw[d] = inw[i];
        }
        __syncthreads();
        for (int i = t; i < eb; i += 256) {
            rows_s[base + i] = outr[i];
            ws_s[base + i] = outw[i];
        }
        if (t < ncount) {
            ptr[j0 + t] = base + ex[t];
            float s = 0.f;
            for (int i = ex[t]; i < ex[t] + h[t]; ++i) s += outw[i];
            dis[j0 + t] = rsqrtf(s + 1.0f);
        }
    } else {  // fallback (eb > CAP): global two-pass, still correct
        for (int i = t; i < eb; i += 256) atomicAdd(&h[(bktrec[base + i].x >> 20) & 63], 1);
        __syncthreads();
        if (t == 0) {
            int run = 0;
            for (int j = 0; j < NPB; ++j) { ex[j] = run; run += h[j]; }
            ex[NPB] = run;
        }
        __syncthreads();
        for (int i = t; i < eb; i += 256) {
            int2 rc = bktrec[base + i];
            int cl = (rc.x >> 20) & 63;
            int d = ex[cl] + atomicAdd(&cu[cl], 1);
            rows_s[base + d] = rc.x & 0xFFFFF;
            ws_s[base + d] = __int_as_float(rc.y);
        }
        __syncthreads();
        if (t < ncount) {
            ptr[j0 + t] = base + ex[t];
            float s = 0.f;
            for (int i = base + ex[t]; i < base + ex[t] + h[t]; ++i) s += ws_s[i];
            dis[j0 + t] = rsqrtf(s + 1.0f);
        }
    }
    if (b == NB - 1 && t == 0) ptr[n] = E;
    if (b == NB - 1 && t < 8) {  // zero pad: masked over-reads see row 0 / w 0
        rows_s[E + t] = 0;
        ws_s[E + t] = 0.f;
    }
}

__device__ inline uint32 pack2h(float a, float b) {
    unsigned short ua = __builtin_bit_cast(unsigned short, (_Float16)a);
    unsigned short ub = __builtin_bit_cast(unsigned short, (_Float16)b);
    return (uint32)ua | ((uint32)ub << 16);
}
__device__ inline float h2lo(uint32 g) {
    return (float)__builtin_bit_cast(_Float16, (unsigned short)(g & 0xFFFFu));
}
__device__ inline float h2hi(uint32 g) {
    return (float)__builtin_bit_cast(_Float16, (unsigned short)(g >> 16));
}

// Byte offset of fp16 element k within a 256B fragment-ordered row (same
// permutation applied to A and B keeps D = A*B invariant).
__device__ inline int kposb(int k) {
    return ((k >> 5) << 6) + (((k >> 2) & 3) << 4) + (((k >> 4) & 1) << 3) + ((k & 3) << 1);
}

// ---------------------------------------------------------------------------
// Y[n,DOUT] = dis[row] * (X[n,128] @ W[128,DOUT]) via mfma_f32_16x16x32_f16.
// ---------------------------------------------------------------------------
template <int DOUT, bool PACKED>
__global__ __launch_bounds__(256, 2) void mgemm_kernel(const void* __restrict__ Xv,
                                                       const float* __restrict__ W,
                                                       const float* __restrict__ dis,
                                                       unsigned short* __restrict__ Y,
                                                       int n) {
    constexpr int NC = DOUT / 16;
    __shared__ __align__(16) unsigned short Xl[128 * 128];
    __shared__ __align__(16) unsigned short Wl[DOUT * 128];
    const int t = threadIdx.x;
    const int row0 = blockIdx.x * 128;

    for (int i = t * 4; i < 128 * 128; i += 1024) {
        int r = i >> 7, k = i & 127;
        uint2 st;
        if (PACKED) {
            uint2 v = {0u, 0u};
            if (row0 + r < n)
                v = *(const uint2*)((const uint32*)Xv + (size_t)(row0 + r) * 64 + (k >> 1));
            st = v;
        } else {
            float4 v = {0.f, 0.f, 0.f, 0.f};
            if (row0 + r < n)
                v = *(const float4*)((const float*)Xv + (size_t)(row0 + r) * 128 + k);
            st.x = pack2h(v.x, v.y);
            st.y = pack2h(v.z, v.w);
        }
        *(uint2*)((char*)Xl + r * 256 + (kposb(k) ^ ((r & 7) << 4))) = st;
    }
    for (int i = t; i < 128 * (DOUT / 4); i += 256) {
        int k = i / (DOUT / 4);
        int c0 = (i % (DOUT / 4)) * 4;
        float4 wv = *(const float4*)(W + (size_t)k * DOUT + c0);
        float a[4] = {wv.x, wv.y, wv.z, wv.w};
        int kb = kposb(k);
#pragma unroll
        for (int j = 0; j < 4; ++j) {
            int c = c0 + j;
            *(unsigned short*)((char*)Wl + c * 256 + (kb ^ ((c & 7) << 4))) =
                __builtin_bit_cast(unsigned short, (_Float16)a[j]);
        }
    }
    __syncthreads();

    const int l = t & 63;
    const int w = t >> 6;
    const int lr = l & 15;
    const int lq = l >> 4;
    const int rbase = w * 32;
    const int swz = (lr & 7) << 4;

    f32x4 acc[2][NC];
#pragma unroll
    for (int i = 0; i < 2; ++i)
#pragma unroll
        for (int c = 0; c < NC; ++c) acc[i][c] = (f32x4){0.f, 0.f, 0.f, 0.f};

#pragma unroll
    for (int ks = 0; ks < 4; ++ks) {
        const int fo = ks * 64 + lq * 16;
        f16x8 a0 = *(const f16x8*)((const char*)Xl + (rbase + lr) * 256 + (fo ^ swz));
        f16x8 a1 = *(const f16x8*)((const char*)Xl + (rbase + 16 + lr) * 256 + (fo ^ swz));
#pragma unroll
        for (int c = 0; c < NC; ++c) {
            f16x8 b = *(const f16x8*)((const char*)Wl + (c * 16 + lr) * 256 + (fo ^ swz));
            acc[0][c] = __builtin_amdgcn_mfma_f32_16x16x32_f16(a0, b, acc[0][c], 0, 0, 0);
            acc[1][c] = __builtin_amdgcn_mfma_f32_16x16x32_f16(a1, b, acc[1][c], 0, 0, 0);
        }
    }

#pragma unroll
    for (int i = 0; i < 2; ++i) {
#pragma unroll
        for (int reg = 0; reg < 4; ++reg) {
            int row = row0 + rbase + i * 16 + lq * 4 + reg;
            if (row < n) {
                float dvv = dis[row];
#pragma unroll
                for (int c = 0; c < NC; ++c)
                    Y[(size_t)row * DOUT + c * 16 + lr] =
                        __builtin_bit_cast(unsigned short, (_Float16)(dvv * acc[i][c][reg]));
            }
        }
    }
}

// One wave per node, D=128: lane covers dims 2*lane..2*lane+1 (one fp16x2).
// table pre-scaled by dis[row]; edge meta via wave-uniform scalar loads.
__global__ __launch_bounds__(256) void prop128_kernel(const uint32* __restrict__ xwb,
                                                      const float* __restrict__ dis,
                                                      const int* __restrict__ ptr,
                                                      const int* __restrict__ rows_s,
                                                      const float* __restrict__ ws_s,
                                                      const float* __restrict__ bias,
                                                      uint32* __restrict__ out, int n) {
    const int wid = threadIdx.x >> 6;
    const int lane = threadIdx.x & 63;
    const int v = blockIdx.x * 4 + wid;
    if (v >= n) return;

    const int beg = __builtin_amdgcn_readfirstlane(ptr[v]);
    const int end = __builtin_amdgcn_readfirstlane(ptr[v + 1]);
    const float dv = dis[v];

    float acc0 = 0.f, acc1 = 0.f;
    int e = beg;
    int head = (beg + 3) & ~3;
    if (head > end) head = end;
    for (; e < head; ++e) {
        int r = rows_s[e];
        float w = ws_s[e];
        uint32 g = xwb[(size_t)r * 64 + lane];
        acc0 += w * h2lo(g);
        acc1 += w * h2hi(g);
    }
#pragma unroll 4
    for (; e + 4 <= end; e += 4) {
        int4 r4 = *(const int4*)(rows_s + e);
        float4 w4 = *(const float4*)(ws_s + e);
        uint32 g0 = xwb[(size_t)r4.x * 64 + lane];
        uint32 g1 = xwb[(size_t)r4.y * 64 + lane];
        uint32 g2 = xwb[(size_t)r4.z * 64 + lane];
        uint32 g3 = xwb[(size_t)r4.w * 64 + lane];
        acc0 += w4.x * h2lo(g0); acc1 += w4.x * h2hi(g0);
        acc0 += w4.y * h2lo(g1); acc1 += w4.y * h2hi(g1);
        acc0 += w4.z * h2lo(g2); acc1 += w4.z * h2hi(g2);
        acc0 += w4.w * h2lo(g3); acc1 += w4.w * h2hi(g3);
    }
    for (; e < end; ++e) {
        int r = rows_s[e];
        float w = ws_s[e];
        uint32 g = xwb[(size_t)r * 64 + lane];
        acc0 += w * h2lo(g);
        acc1 += w * h2hi(g);
    }

    uint32 g = xwb[(size_t)v * 64 + lane];  // self: dv*table[v] = dis^2*xw[v]
    float r0 = dv * (acc0 + h2lo(g)) + bias[lane * 2];
    float r1 = dv * (acc1 + h2hi(g)) + bias[lane * 2 + 1];
    r0 = fmaxf(r0, 0.f);
    r1 = fmaxf(r1, 0.f);
    out[(size_t)v * 64 + lane] = pack2h(r0, r1);
}

// One wave per node, D=64: lane halves process 2 edges/iter; dims via
// dlane=lane&31 (fp16x2 each). shfl_xor(32) combine; f32 final output.
__global__ __launch_bounds__(256) void prop64_kernel(const uint32* __restrict__ xwb,
                                                     const float* __restrict__ dis,
                                                     const int* __restrict__ ptr,
                                                     const int* __restrict__ rows_s,
                                                     const float* __restrict__ ws_s,
                                                     const float* __restrict__ bias,
                                                     float* __restrict__ out, int n) {
    const int wid = threadIdx.x >> 6;
    const int lane = threadIdx.x & 63;
    const int half = lane >> 5;
    const int dlane = lane & 31;
    const int v = blockIdx.x * 4 + wid;
    if (v >= n) return;

    const int beg = __builtin_amdgcn_readfirstlane(ptr[v]);
    const int end = __builtin_amdgcn_readfirstlane(ptr[v + 1]);
    const float dv = dis[v];

    float acc0 = 0.f, acc1 = 0.f;
    int e = beg;
    int head = (beg + 3) & ~3;
    if (head > end) head = end;
    for (; e < head; ++e) {
        int r = rows_s[e];
        float w = half ? 0.f : ws_s[e];
        uint32 g = xwb[(size_t)r * 32 + dlane];
        acc0 += w * h2lo(g);
        acc1 += w * h2hi(g);
    }
#pragma unroll 4
    for (; e + 4 <= end; e += 4) {
        int4 r4 = *(const int4*)(rows_s + e);
        float4 w4 = *(const float4*)(ws_s + e);
        int rA = half ? r4.y : r4.x;
        float wA = half ? w4.y : w4.x;
        int rB = half ? r4.w : r4.z;
        float wB = half ? w4.w : w4.z;
        uint32 gA = xwb[(size_t)rA * 32 + dlane];
        uint32 gB = xwb[(size_t)rB * 32 + dlane];
        acc0 += wA * h2lo(gA); acc1 += wA * h2hi(gA);
        acc0 += wB * h2lo(gB); acc1 += wB * h2hi(gB);
    }
    if (e + 2 <= end) {
        int2 r2 = *(const int2*)(rows_s + e);
        float2 w2 = *(const float2*)(ws_s + e);
        int r = half ? r2.y : r2.x;
        float w = half ? w2.y : w2.x;
        uint32 g = xwb[(size_t)r * 32 + dlane];
        acc0 += w * h2lo(g);
        acc1 += w * h2hi(g);
        e += 2;
    }
    if (e < end) {
        int r = rows_s[e];
        float w = half ? 0.f : ws_s[e];
        uint32 g = xwb[(size_t)r * 32 + dlane];
        acc0 += w * h2lo(g);
        acc1 += w * h2hi(g);
    }
    acc0 += __shfl_xor(acc0, 32);
    acc1 += __shfl_xor(acc1, 32);

    if (lane < 32) {
        uint32 g = xwb[(size_t)v * 32 + lane];
        float r0 = dv * (acc0 + h2lo(g)) + bias[lane * 2];
        float r1 = dv * (acc1 + h2hi(g)) + bias[lane * 2 + 1];
        float2 o = {r0, r1};
        *(float2*)(out + (size_t)v * 64 + lane * 2) = o;
    }
}

extern "C" void kernel_launch(void* const* d_in, const int* in_sizes, int n_in,
                              void* d_out, int out_size, void* d_ws, size_t ws_size,
                              hipStream_t stream) {
    const float* x  = (const float*)d_in[0];
    const void*  ei = d_in[1];
    const float* ew = (const float*)d_in[2];
    const float* W1 = (const float*)d_in[3];
    const float* b1 = (const float*)d_in[4];
    const float* W2 = (const float*)d_in[5];
    const float* b2 = (const float*)d_in[6];
    float* out = (float*)d_out;

    const int n = in_sizes[0] / 128;
    const int E = in_sizes[2];
    const int NB = (n + NPB - 1) >> NPBSH;
    const int chunk = (E + PBLK - 1) / PBLK;

    char* p = (char*)d_ws;
    size_t o = 0;
    auto alloc = [&](size_t bytes) -> void* {
        void* q = p + o;
        o += (bytes + 255) & ~(size_t)255;
        return q;
    };
    int*    cnt_bb   = (int*)alloc((size_t)PBLK * NB * 4);
    int*    boff_rel = (int*)alloc((size_t)PBLK * NB * 4);
    int*    tb       = (int*)alloc((size_t)NB * 4);
    int*    bstart   = (int*)alloc(((size_t)NB + 1) * 4);
    int*    ptr      = (int*)alloc(((size_t)n + 1) * 4);
    float*  dis      = (float*)alloc((size_t)n * 4);
    int2*   bktrec   = (int2*)alloc((size_t)E * 8);
    int*    rows_s   = (int*)alloc(((size_t)E + 8) * 4);
    float*  ws_s     = (float*)alloc(((size_t)E + 8) * 4);
    uint32* bufA     = (uint32*)alloc((size_t)n * 64 * 4);  // dis-scaled xw tables
    uint32* bufB     = (uint32*)alloc((size_t)n * 64 * 4);  // h fp16x2

    const int gblk = (n + 127) / 128;

    p1_hist<<<PBLK, 512, NB * 4, stream>>>(ei, E, NB, chunk, cnt_bb);
    s1_colscan<<<NB, PBLK, 0, stream>>>(cnt_bb, boff_rel, tb, NB);
    scan_kernel<<<1, 1024, 0, stream>>>(tb, bstart, NB);
    p2_scatter<<<PBLK, 512, NB * 4, stream>>>(ei, ew, E, NB, chunk, bstart, boff_rel, bktrec);
    p3_build<<<NB, 256, 0, stream>>>(bstart, bktrec, ptr, rows_s, ws_s, dis, n, NB, E);

    mgemm_kernel<128, false><<<gblk, 256, 0, stream>>>(x, W1, dis, (unsigned short*)bufA, n);
    prop128_kernel<<<(n + 3) / 4, 256, 0, stream>>>(bufA, dis, ptr, rows_s, ws_s, b1, bufB, n);
    mgemm_kernel<64, true><<<gblk, 256, 0, stream>>>(bufB, W2, dis, (unsigned short*)bufA, n);
    prop64_kernel<<<(n + 3) / 4, 256, 0, stream>>>(bufA, dis, ptr, rows_s, ws_s, b2, out, n);
}